// Round 8
// baseline (246.573 us; speedup 1.0000x reference)
//
#include <hip/hip_runtime.h>
#include <type_traits>
#include <utility>

#define B_ 2
#define S_ 2048
#define D_ 1024
#define H_ 16
#define HD_ 64
#define KDIM 1024

typedef __attribute__((ext_vector_type(8))) short    s16x8;
typedef __attribute__((ext_vector_type(8))) _Float16 h16x8;
typedef __attribute__((ext_vector_type(4))) float    f32x4;
typedef __attribute__((ext_vector_type(4))) int      i32x4;
typedef __attribute__((ext_vector_type(2))) int      i32x2;

// --- MFMA operand-type hedge (fp16) ---
template <typename T, typename = void> struct mfma_takes : std::false_type {};
template <typename T>
struct mfma_takes<T, std::void_t<decltype(__builtin_amdgcn_mfma_f32_16x16x32_f16(
    std::declval<T>(), std::declval<T>(), std::declval<f32x4>(), 0, 0, 0))>>
    : std::true_type {};
using frag8 = std::conditional_t<mfma_takes<h16x8>::value, h16x8, s16x8>;

__device__ __forceinline__ f32x4 mfma_f16(frag8 a, frag8 b, f32x4 c) {
  return __builtin_amdgcn_mfma_f32_16x16x32_f16(a, b, c, 0, 0, 0);
}

__device__ __forceinline__ short f2h(float f) {  // RTNE f32 -> fp16 bits
  _Float16 h = (_Float16)f;
  short s; __builtin_memcpy(&s, &h, 2);
  return s;
}
__device__ __forceinline__ frag8 ld_frag(const short* p) {
  return __builtin_bit_cast(frag8, *(const i32x4*)p);
}
__device__ __forceinline__ frag8 cvt_frag(f32x4 a, f32x4 b) {
  _Float16 h[8] = { (_Float16)a[0], (_Float16)a[1], (_Float16)a[2], (_Float16)a[3],
                    (_Float16)b[0], (_Float16)b[1], (_Float16)b[2], (_Float16)b[3] };
  frag8 f; __builtin_memcpy(&f, h, 16); return f;
}
__device__ __forceinline__ float fast_exp2(float x) {
  return __builtin_amdgcn_exp2f(x);
}

typedef __attribute__((address_space(1))) const void gvoid;
typedef __attribute__((address_space(3))) void lvoid;
__device__ __forceinline__ void async_copy16(const void* g, void* l) {
  __builtin_amdgcn_global_load_lds((gvoid*)g, (lvoid*)l, 16, 0, 0);
}

#define RAW_BARRIER() asm volatile("s_barrier" ::: "memory")
#define WAITCNT_VM(n) asm volatile("s_waitcnt vmcnt(" #n ")" ::: "memory")

// ---------------------------------------------------------------------------
// Weight-only fp32 -> fp16 convert (activations are consumed fp32 by QKV GEMM)
// 4 x 1,048,576 elems, 8/thread -> 2048 blocks.
// ---------------------------------------------------------------------------
__global__ __launch_bounds__(256)
void conv_w(const float* __restrict__ Wq, const float* __restrict__ Wk,
            const float* __restrict__ Wv, const float* __restrict__ Wo,
            short* __restrict__ wq, short* __restrict__ wk,
            short* __restrict__ wv, short* __restrict__ wo) {
  const int blk = blockIdx.x;
  const float* src; short* dst; int base;
  if (blk < 512)       { src = Wq; dst = wq; base = blk; }
  else if (blk < 1024) { src = Wk; dst = wk; base = blk - 512; }
  else if (blk < 1536) { src = Wv; dst = wv; base = blk - 1024; }
  else                 { src = Wo; dst = wo; base = blk - 1536; }
  const int i = base * 2048 + threadIdx.x * 8;
  float4 a0 = *(const float4*)(src + i);
  float4 a1 = *(const float4*)(src + i + 4);
  short h[8] = { f2h(a0.x), f2h(a0.y), f2h(a0.z), f2h(a0.w),
                 f2h(a1.x), f2h(a1.y), f2h(a1.z), f2h(a1.w) };
  i32x4 ph; __builtin_memcpy(&ph, h, 16);
  *(i32x4*)(dst + i) = ph;
}

// ---------------------------------------------------------------------------
// QKV projection GEMM: A = fp32 activations staged raw via global_load_lds
// (converted to fp16 in registers after LDS read); W = fp16. Tile 128x128,
// BK=32, double-buffered, raw s_barrier + fine vmcnt (vmcnt(0) peel on last).
// LDS: Asf 32KB + Bs 16KB = 48KB -> 3 blocks/CU.
// omode 1 -> fp16 [B,H,S,Hd] (scaled, +bias); omode 2 -> fp16 Vt [B,H,Hd,S].
// ---------------------------------------------------------------------------
__global__ __launch_bounds__(256, 3)
void gemm_qkv(const float* __restrict__ qa, const float* __restrict__ ka,
              const float* __restrict__ va, const short* __restrict__ wq,
              const short* __restrict__ wk, const short* __restrict__ wv,
              const float* __restrict__ bq, const float* __restrict__ bk,
              const float* __restrict__ bv, short* __restrict__ Qf,
              short* __restrict__ Kf, short* __restrict__ Vt, float QS) {
  __shared__ float Asf[2 * 4096];   // 2 x 128x32 fp32 = 32KB
  __shared__ short Bs[2 * 4096];    // 2 x 128x32 fp16 = 16KB

  const int z = blockIdx.z;
  const float* Ap = z == 0 ? qa : z == 1 ? ka : va;
  const short* Wp = z == 0 ? wq : z == 1 ? wk : wv;
  const float* bias = z == 0 ? bq : z == 1 ? bk : bv;
  short* Out = z == 0 ? Qf : z == 1 ? Kf : Vt;
  const float scale = z == 0 ? QS : 1.0f;
  const int omode = z == 2 ? 2 : 1;
  const int bm = blockIdx.y, bn = blockIdx.x;

  const int t = threadIdx.x, wave = t >> 6, lane = t & 63;
  const int laneN = lane & 15, quad = lane >> 4;
  const int wm = wave & 1, wn = wave >> 1;

  f32x4 acc[4][4];
#pragma unroll
  for (int i = 0; i < 4; ++i)
#pragma unroll
    for (int j = 0; j < 4; ++j)
#pragma unroll
      for (int r = 0; r < 4; ++r) acc[i][j][r] = 0.f;

  auto stage = [&](int buf, int kk) {
    // A fp32: 128 rows x 8 chunks(4 floats) = 1024 chunks, 4/thread
#pragma unroll
    for (int j = 0; j < 4; ++j) {
      const int chunk = j * 256 + t;
      const int row = chunk >> 3;
      const int g = (chunk & 7) ^ (row & 7);
      async_copy16(Ap + (size_t)(bm * 128 + row) * KDIM + kk + g * 4,
                   Asf + buf * 4096 + chunk * 4);
    }
    // W fp16: 128 rows x 4 chunks(8 shorts) = 512 chunks, 2/thread
#pragma unroll
    for (int j = 0; j < 2; ++j) {
      const int chunk = j * 256 + t;
      const int row = chunk >> 2;
      const int g = (chunk & 3) ^ ((row >> 1) & 3);
      async_copy16(Wp + (size_t)(bn * 128 + row) * KDIM + kk + g * 8,
                   Bs + buf * 4096 + chunk * 8);
    }
  };

  stage(0, 0);
  int buf = 0;
  for (int kk = 0; kk < KDIM; kk += 32, buf ^= 1) {
    if (kk + 32 < KDIM) {
      stage(buf ^ 1, kk + 32);
      WAITCNT_VM(6);
    } else {
      WAITCNT_VM(0);
    }
    RAW_BARRIER();

    frag8 aF[4], bF[4];
#pragma unroll
    for (int mi = 0; mi < 4; ++mi) {
      const int row = wm * 64 + mi * 16 + laneN;
      const float* rp = Asf + buf * 4096 + row * 32;
      f32x4 a0 = *(const f32x4*)(rp + (((quad * 2) ^ (row & 7)) * 4));
      f32x4 a1 = *(const f32x4*)(rp + (((quad * 2 + 1) ^ (row & 7)) * 4));
      aF[mi] = cvt_frag(a0, a1);
    }
#pragma unroll
    for (int ni = 0; ni < 4; ++ni) {
      const int row = wn * 64 + ni * 16 + laneN;
      bF[ni] = ld_frag(Bs + buf * 4096 + row * 32 +
                       ((quad ^ ((row >> 1) & 3)) * 8));
    }
#pragma unroll
    for (int mi = 0; mi < 4; ++mi)
#pragma unroll
      for (int ni = 0; ni < 4; ++ni)
        acc[mi][ni] = mfma_f16(aF[mi], bF[ni], acc[mi][ni]);
    RAW_BARRIER();
  }

  // Epilogue. C/D: col = lane&15, row = quad*4 + reg.
#pragma unroll
  for (int mi = 0; mi < 4; ++mi)
#pragma unroll
    for (int ni = 0; ni < 4; ++ni) {
      const int colg = bn * 128 + wn * 64 + ni * 16 + laneN;
      const float bb = bias[colg];
      if (omode == 2) {
        // Vt [B,H,Hd,S]: r -> 4 consecutive s, same hd -> one b64 store
        const int rowg0 = bm * 128 + wm * 64 + mi * 16 + quad * 4;
        const int b = rowg0 >> 11, s0 = rowg0 & 2047;
        const int h = colg >> 6, hd = colg & 63;
        short pk[4];
#pragma unroll
        for (int r = 0; r < 4; ++r) pk[r] = f2h(acc[mi][ni][r] + bb);
        i32x2 w; __builtin_memcpy(&w, pk, 8);
        *(i32x2*)(Out + (((size_t)(b * H_ + h)) * HD_ + hd) * S_ + s0) = w;
      } else {
#pragma unroll
        for (int r = 0; r < 4; ++r) {
          const int rowg = bm * 128 + wm * 64 + mi * 16 + quad * 4 + r;
          const int b = rowg >> 11, s = rowg & 2047;
          const int h = colg >> 6, hd = colg & 63;
          Out[(((size_t)(b * H_ + h)) * S_ + s) * HD_ + hd] =
              f2h((acc[mi][ni][r] + bb) * scale);
        }
      }
    }
}

// ---------------------------------------------------------------------------
// O projection: fp16 A (attn out) x fp16 Wo -> fp32 out. Tile 128x128, BK=32,
// double-buffered global_load_lds, XOR-swizzled LDS.
// ---------------------------------------------------------------------------
__global__ __launch_bounds__(256, 3)
void gemm_out(const short* __restrict__ Ap, const short* __restrict__ Wp,
              const float* __restrict__ bias, float* __restrict__ Out) {
  __shared__ short As[2 * 4096];
  __shared__ short Bs[2 * 4096];
  const int bm = blockIdx.y, bn = blockIdx.x;
  const int t = threadIdx.x, wave = t >> 6, lane = t & 63;
  const int laneN = lane & 15, quad = lane >> 4;
  const int wm = wave & 1, wn = wave >> 1;

  f32x4 acc[4][4];
#pragma unroll
  for (int i = 0; i < 4; ++i)
#pragma unroll
    for (int j = 0; j < 4; ++j)
#pragma unroll
      for (int r = 0; r < 4; ++r) acc[i][j][r] = 0.f;

  auto stage = [&](int buf, int kk) {
#pragma unroll
    for (int j = 0; j < 2; ++j) {
      const int chunk = j * 256 + t;
      const int row = chunk >> 2;
      const int g = (chunk & 3) ^ ((row >> 1) & 3);
      async_copy16(Ap + (size_t)(bm * 128 + row) * KDIM + kk + g * 8,
                   As + buf * 4096 + chunk * 8);
      async_copy16(Wp + (size_t)(bn * 128 + row) * KDIM + kk + g * 8,
                   Bs + buf * 4096 + chunk * 8);
    }
  };

  stage(0, 0);
  int buf = 0;
  for (int kk = 0; kk < KDIM; kk += 32, buf ^= 1) {
    if (kk + 32 < KDIM) {
      stage(buf ^ 1, kk + 32);
      WAITCNT_VM(4);
    } else {
      WAITCNT_VM(0);
    }
    RAW_BARRIER();

    frag8 aF[4], bF[4];
#pragma unroll
    for (int mi = 0; mi < 4; ++mi) {
      const int row = wm * 64 + mi * 16 + laneN;
      aF[mi] = ld_frag(As + buf * 4096 + row * 32 +
                       ((quad ^ ((row >> 1) & 3)) * 8));
    }
#pragma unroll
    for (int ni = 0; ni < 4; ++ni) {
      const int row = wn * 64 + ni * 16 + laneN;
      bF[ni] = ld_frag(Bs + buf * 4096 + row * 32 +
                       ((quad ^ ((row >> 1) & 3)) * 8));
    }
#pragma unroll
    for (int mi = 0; mi < 4; ++mi)
#pragma unroll
      for (int ni = 0; ni < 4; ++ni)
        acc[mi][ni] = mfma_f16(aF[mi], bF[ni], acc[mi][ni]);
    RAW_BARRIER();
  }

#pragma unroll
  for (int mi = 0; mi < 4; ++mi)
#pragma unroll
    for (int ni = 0; ni < 4; ++ni) {
      const int colg = bn * 128 + wn * 64 + ni * 16 + laneN;
      const float bb = bias[colg];
#pragma unroll
      for (int r = 0; r < 4; ++r) {
        const int rowg = bm * 128 + wm * 64 + mi * 16 + quad * 4 + r;
        Out[(size_t)rowg * 1024 + colg] = acc[mi][ni][r] + bb;
      }
    }
}

// ---------------------------------------------------------------------------
// Flash attention, fp16, 512 threads = 8 waves x 16 q-rows = 128 q/block.
// XCD-aware 1-D grid: blk&7 selects XCD-group; each group owns 4 (h,b) pairs
// so K/V stay L2-resident per XCD (2MB < 4MB). Transposed scores
// mfma(A=K,B=Q) -> S^T; in-lane softmax + 2 shuffles; PV mfma(A=Vt,B=P) ->
// O^T. Double-buffered async K/V staging (vmcnt(0) peel), exp2-domain
// softmax (Q pre-scaled 8*log2e). LDS 50KB -> 2 blocks/CU, 16 waves/CU.
// ---------------------------------------------------------------------------
__global__ __launch_bounds__(512, 2)
void attn(const short* __restrict__ Qf, const short* __restrict__ Kf,
          const short* __restrict__ Vt_, short* __restrict__ Ow) {
  __shared__ short Ks[2 * 4096];
  __shared__ short Vts[2 * 4096];
  __shared__ short Ps[8][16 * 72];  // per-wave P strip [q][k], stride 72

  // XCD-locality decode: 512 blocks, 8 groups x 4 (h,b) pairs x 16 q-tiles
  const int blk = blockIdx.x;
  const int xcd = blk & 7, local = blk >> 3;       // local 0..63
  const int pair = xcd * 4 + (local >> 4);         // 0..31
  const int h = pair & 15, b = pair >> 4, qt = local & 15;
  const size_t head = ((size_t)b * H_ + h) * (size_t)S_ * HD_;

  const int t = threadIdx.x;
  const int wave = t >> 6, lane = t & 63;
  const int laneN = lane & 15, quad = lane >> 4;

  // Q frags direct from global (B-operand layout); wave owns 16 q rows
  frag8 qf[2];
  {
    const size_t row = (size_t)qt * 128 + wave * 16 + laneN;
#pragma unroll
    for (int half = 0; half < 2; ++half)
      qf[half] = ld_frag(Qf + head + row * HD_ + half * 32 + quad * 8);
  }

  f32x4 o[4];          // O^T: row d = dt*16+quad*4+r, col q = laneN
  float m_r = -1e30f, l_r = 0.f;
#pragma unroll
  for (int i = 0; i < 4; ++i)
#pragma unroll
    for (int j = 0; j < 4; ++j) o[i][j] = 0.f;

  auto stage = [&](int buf, int kt) {
    const int chunk = t;                 // 0..511
    const int row = chunk >> 3;          // 0..63
    const int g = (chunk & 7) ^ (row & 7);
    const int ldsoff = buf * 4096 + chunk * 8;
    async_copy16(Kf + head + (size_t)(kt * 64 + row) * HD_ + g * 8, Ks + ldsoff);
    async_copy16(Vt_ + head + (size_t)row * S_ + kt * 64 + g * 8, Vts + ldsoff);
  };

  stage(0, 0);
  int buf = 0;
  for (int kt = 0; kt < 32; ++kt, buf ^= 1) {
    if (kt + 1 < 32) {
      stage(buf ^ 1, kt + 1);
      WAITCNT_VM(2);
    } else {
      WAITCNT_VM(0);
    }
    RAW_BARRIER();

    // Vt frags (A-operand of PV): rows d = dt*16+laneN
    frag8 vf[4][2];
#pragma unroll
    for (int dt = 0; dt < 4; ++dt) {
      const int row = dt * 16 + laneN;
#pragma unroll
      for (int half = 0; half < 2; ++half)
        vf[dt][half] = ld_frag(Vts + buf * 4096 + row * 64 +
                               (((half * 4 + quad) ^ (row & 7)) * 8));
    }

    // S^T = K.Q^T: per lane 16 logits for q=laneN, k = nt*16+quad*4+r
    f32x4 s[4];
#pragma unroll
    for (int nt = 0; nt < 4; ++nt) {
      const int row = nt * 16 + laneN;
      const int o0 = buf * 4096 + row * 64 + ((quad ^ (row & 7)) * 8);
      const int o1 = buf * 4096 + row * 64 + (((quad + 4) ^ (row & 7)) * 8);
      frag8 k0 = ld_frag(Ks + o0), k1 = ld_frag(Ks + o1);
      f32x4 acc;
#pragma unroll
      for (int j = 0; j < 4; ++j) acc[j] = 0.f;
      acc = mfma_f16(k0, qf[0], acc);
      acc = mfma_f16(k1, qf[1], acc);
      s[nt] = acc;
    }

    // online softmax (exp2 domain): in-lane reduce 16 + xor16/xor32
    {
      float mx = -1e30f;
#pragma unroll
      for (int nt = 0; nt < 4; ++nt)
#pragma unroll
        for (int r = 0; r < 4; ++r) mx = fmaxf(mx, s[nt][r]);
      mx = fmaxf(mx, __shfl_xor(mx, 16));
      mx = fmaxf(mx, __shfl_xor(mx, 32));
      const float mn = fmaxf(m_r, mx);
      const float al = fast_exp2(m_r - mn);
      m_r = mn;
      float rs = 0.f;
#pragma unroll
      for (int nt = 0; nt < 4; ++nt)
#pragma unroll
        for (int r = 0; r < 4; ++r) {
          const float p = fast_exp2(s[nt][r] - mn);
          s[nt][r] = p; rs += p;
        }
      rs += __shfl_xor(rs, 16);
      rs += __shfl_xor(rs, 32);
      l_r = l_r * al + rs;
#pragma unroll
      for (int dt = 0; dt < 4; ++dt)
#pragma unroll
        for (int r = 0; r < 4; ++r) o[dt][r] *= al;
    }

    // P pack: 4 consecutive k per nt -> one b64 LDS write; strip [q][k]
#pragma unroll
    for (int nt = 0; nt < 4; ++nt) {
      short pk[4] = { f2h(s[nt][0]), f2h(s[nt][1]),
                      f2h(s[nt][2]), f2h(s[nt][3]) };
      i32x2 w; __builtin_memcpy(&w, pk, 8);
      *(i32x2*)&Ps[wave][laneN * 72 + nt * 16 + quad * 4] = w;
    }
    // B-operand P frags (per-wave strip; in-order DS within a wave)
    const frag8 p0 = ld_frag(&Ps[wave][laneN * 72 + quad * 8]);
    const frag8 p1 = ld_frag(&Ps[wave][laneN * 72 + 32 + quad * 8]);
#pragma unroll
    for (int dt = 0; dt < 4; ++dt) {
      o[dt] = mfma_f16(vf[dt][0], p0, o[dt]);
      o[dt] = mfma_f16(vf[dt][1], p1, o[dt]);
    }
    RAW_BARRIER();
  }

  // epilogue: O^T -> Ow[B,S,D] fp16; lane owns q, 4 consecutive d per dt
  {
    const float inv = 1.0f / l_r;
    const int sg = qt * 128 + wave * 16 + laneN;
    short* dst = Ow + ((size_t)b * S_ + sg) * D_ + h * HD_;
#pragma unroll
    for (int dt = 0; dt < 4; ++dt) {
      short pk[4] = { f2h(o[dt][0] * inv), f2h(o[dt][1] * inv),
                      f2h(o[dt][2] * inv), f2h(o[dt][3] * inv) };
      i32x2 w; __builtin_memcpy(&w, pk, 8);
      *(i32x2*)(dst + dt * 16 + quad * 4) = w;
    }
  }
}

// ---------------------------------------------------------------------------
extern "C" void kernel_launch(void* const* d_in, const int* in_sizes, int n_in,
                              void* d_out, int out_size, void* d_ws, size_t ws_size,
                              hipStream_t stream) {
  const float* q  = (const float*)d_in[0];
  const float* k  = (const float*)d_in[1];
  const float* v  = (const float*)d_in[2];
  const float* Wq = (const float*)d_in[3];
  const float* bq = (const float*)d_in[4];
  const float* Wk = (const float*)d_in[5];
  const float* bk = (const float*)d_in[6];
  const float* Wv = (const float*)d_in[7];
  const float* bv = (const float*)d_in[8];
  const float* Wo = (const float*)d_in[9];
  const float* bo = (const float*)d_in[10];

  const size_t NTOK = (size_t)B_ * S_ * D_;   // 4,194,304
  const size_t NW   = (size_t)D_ * D_;        // 1,048,576
  short* p = (short*)d_ws;
  short* wq = p; p += NW;    short* wk = p; p += NW;
  short* wv = p; p += NW;    short* wo = p; p += NW;
  short* Qf = p; p += NTOK;  short* Kf = p; p += NTOK;
  short* Vt = p; p += NTOK;  short* Ow = p; p += NTOK;

  dim3 blk(256);

  conv_w<<<2048, blk, 0, stream>>>(Wq, Wk, Wv, Wo, wq, wk, wv, wo);

  const float QS = 11.541560327111707f;  // 8 * log2(e): exp2-domain softmax
  dim3 gqkv(D_ / 128, (B_ * S_) / 128, 3);  // (8, 32, 3) = 768 blocks
  gemm_qkv<<<gqkv, blk, 0, stream>>>(q, k, v, wq, wk, wv, bq, bk, bv,
                                     Qf, Kf, Vt, QS);

  attn<<<dim3(512), dim3(512), 0, stream>>>(Qf, Kf, Vt, Ow);

  dim3 gg(D_ / 128, (B_ * S_) / 128);  // (8, 32)
  gemm_out<<<gg, blk, 0, stream>>>(Ow, wo, bo, (float*)d_out);
}

// Round 10
// 231.434 us; speedup vs baseline: 1.0654x; 1.0654x over previous
//
#include <hip/hip_runtime.h>
#include <type_traits>
#include <utility>

#define B_ 2
#define S_ 2048
#define D_ 1024
#define H_ 16
#define HD_ 64
#define KDIM 1024

typedef __attribute__((ext_vector_type(8))) short    s16x8;
typedef __attribute__((ext_vector_type(8))) _Float16 h16x8;
typedef __attribute__((ext_vector_type(4))) float    f32x4;
typedef __attribute__((ext_vector_type(4))) int      i32x4;
typedef __attribute__((ext_vector_type(2))) int      i32x2;

// --- MFMA operand-type hedge (fp16) ---
template <typename T, typename = void> struct mfma_takes : std::false_type {};
template <typename T>
struct mfma_takes<T, std::void_t<decltype(__builtin_amdgcn_mfma_f32_16x16x32_f16(
    std::declval<T>(), std::declval<T>(), std::declval<f32x4>(), 0, 0, 0))>>
    : std::true_type {};
using frag8 = std::conditional_t<mfma_takes<h16x8>::value, h16x8, s16x8>;

__device__ __forceinline__ f32x4 mfma_f16(frag8 a, frag8 b, f32x4 c) {
  return __builtin_amdgcn_mfma_f32_16x16x32_f16(a, b, c, 0, 0, 0);
}

__device__ __forceinline__ short f2h(float f) {  // RTNE f32 -> fp16 bits
  _Float16 h = (_Float16)f;
  short s; __builtin_memcpy(&s, &h, 2);
  return s;
}
__device__ __forceinline__ int pk2h(float a, float b) {  // v_cvt_pkrtz 2xfp16
  auto p = __builtin_amdgcn_cvt_pkrtz(a, b);   // __fp16 ext_vector(2)
  int r; __builtin_memcpy(&r, &p, 4); return r;
}
__device__ __forceinline__ frag8 ld_frag(const short* p) {
  return __builtin_bit_cast(frag8, *(const i32x4*)p);
}
__device__ __forceinline__ float fast_exp2(float x) {
  return __builtin_amdgcn_exp2f(x);
}

typedef __attribute__((address_space(1))) const void gvoid;
typedef __attribute__((address_space(3))) void lvoid;
__device__ __forceinline__ void async_copy16(const void* g, void* l) {
  __builtin_amdgcn_global_load_lds((gvoid*)g, (lvoid*)l, 16, 0, 0);
}

#define RAW_BARRIER() asm volatile("s_barrier" ::: "memory")
#define WAITCNT_VM(n) asm volatile("s_waitcnt vmcnt(" #n ")" ::: "memory")

// ---------------------------------------------------------------------------
// Fused fp32 -> fp16 converts: q,k,v (2048 blocks each) + 4 weights (512 each)
// ---------------------------------------------------------------------------
__global__ __launch_bounds__(256)
void conv_all(const float* __restrict__ q, const float* __restrict__ k,
              const float* __restrict__ v, const float* __restrict__ Wq,
              const float* __restrict__ Wk, const float* __restrict__ Wv,
              const float* __restrict__ Wo,
              short* __restrict__ qh, short* __restrict__ kh,
              short* __restrict__ vh, short* __restrict__ wq,
              short* __restrict__ wk, short* __restrict__ wv,
              short* __restrict__ wo) {
  const int blk = blockIdx.x;
  const float* src; short* dst; int base;
  if (blk < 2048)      { src = q;  dst = qh; base = blk; }
  else if (blk < 4096) { src = k;  dst = kh; base = blk - 2048; }
  else if (blk < 6144) { src = v;  dst = vh; base = blk - 4096; }
  else if (blk < 6656) { src = Wq; dst = wq; base = blk - 6144; }
  else if (blk < 7168) { src = Wk; dst = wk; base = blk - 6656; }
  else if (blk < 7680) { src = Wv; dst = wv; base = blk - 7168; }
  else                 { src = Wo; dst = wo; base = blk - 7680; }
  const int i = base * 2048 + threadIdx.x * 8;
  float4 a0 = *(const float4*)(src + i);
  float4 a1 = *(const float4*)(src + i + 4);
  short h[8] = { f2h(a0.x), f2h(a0.y), f2h(a0.z), f2h(a0.w),
                 f2h(a1.x), f2h(a1.y), f2h(a1.z), f2h(a1.w) };
  i32x4 ph; __builtin_memcpy(&ph, h, 16);
  *(i32x4*)(dst + i) = ph;
}

// ---------------------------------------------------------------------------
// QKV projection GEMM, fp16 A & W, tile 128x128, BK=32, double-buffered
// global_load_lds, raw s_barrier + fine vmcnt (vmcnt(0) peel). XCD-aware
// 1-D grid (768): bn = blk&7 so each XCD keeps one W-column tile (256KB)
// L2-resident; g = blk>>3: z = g>>5 (tensor), bm = g&31.
// omode 1 -> fp16 [B,H,S,Hd] (scaled,+bias); omode 2 -> fp16 Vt [B,H,Hd,S].
// ---------------------------------------------------------------------------
__global__ __launch_bounds__(256, 3)
void gemm_qkv(const short* __restrict__ qh, const short* __restrict__ kh,
              const short* __restrict__ vh, const short* __restrict__ wq,
              const short* __restrict__ wk, const short* __restrict__ wv,
              const float* __restrict__ bq, const float* __restrict__ bk,
              const float* __restrict__ bv, short* __restrict__ Qf,
              short* __restrict__ Kf, short* __restrict__ Vt, float QS) {
  __shared__ short As[2 * 4096];
  __shared__ short Bs[2 * 4096];

  const int blk = blockIdx.x;
  const int bn = blk & 7, g = blk >> 3;
  const int z = g >> 5, bm = g & 31;
  const short* Ap = z == 0 ? qh : z == 1 ? kh : vh;
  const short* Wp = z == 0 ? wq : z == 1 ? wk : wv;
  const float* bias = z == 0 ? bq : z == 1 ? bk : bv;
  short* Out = z == 0 ? Qf : z == 1 ? Kf : Vt;
  const float scale = z == 0 ? QS : 1.0f;
  const int omode = z == 2 ? 2 : 1;

  const int t = threadIdx.x, wave = t >> 6, lane = t & 63;
  const int laneN = lane & 15, quad = lane >> 4;
  const int wm = wave & 1, wn = wave >> 1;

  f32x4 acc[4][4];
#pragma unroll
  for (int i = 0; i < 4; ++i)
#pragma unroll
    for (int j = 0; j < 4; ++j)
#pragma unroll
      for (int r = 0; r < 4; ++r) acc[i][j][r] = 0.f;

  auto stage = [&](int buf, int kk) {
#pragma unroll
    for (int j = 0; j < 2; ++j) {
      const int chunk = j * 256 + t;
      const int row = chunk >> 2;
      const int gg = (chunk & 3) ^ ((row >> 1) & 3);
      async_copy16(Ap + (size_t)(bm * 128 + row) * KDIM + kk + gg * 8,
                   As + buf * 4096 + chunk * 8);
      async_copy16(Wp + (size_t)(bn * 128 + row) * KDIM + kk + gg * 8,
                   Bs + buf * 4096 + chunk * 8);
    }
  };

  stage(0, 0);
  int buf = 0;
  for (int kk = 0; kk < KDIM; kk += 32, buf ^= 1) {
    if (kk + 32 < KDIM) {
      stage(buf ^ 1, kk + 32);
      WAITCNT_VM(4);
    } else {
      WAITCNT_VM(0);
    }
    RAW_BARRIER();

    frag8 aF[4], bF[4];
#pragma unroll
    for (int mi = 0; mi < 4; ++mi) {
      const int row = wm * 64 + mi * 16 + laneN;
      aF[mi] = ld_frag(As + buf * 4096 + row * 32 +
                       ((quad ^ ((row >> 1) & 3)) * 8));
    }
#pragma unroll
    for (int ni = 0; ni < 4; ++ni) {
      const int row = wn * 64 + ni * 16 + laneN;
      bF[ni] = ld_frag(Bs + buf * 4096 + row * 32 +
                       ((quad ^ ((row >> 1) & 3)) * 8));
    }
#pragma unroll
    for (int mi = 0; mi < 4; ++mi)
#pragma unroll
      for (int ni = 0; ni < 4; ++ni)
        acc[mi][ni] = mfma_f16(aF[mi], bF[ni], acc[mi][ni]);
    RAW_BARRIER();
  }

  // Epilogue. C/D: col = lane&15, row = quad*4 + reg.
#pragma unroll
  for (int mi = 0; mi < 4; ++mi)
#pragma unroll
    for (int ni = 0; ni < 4; ++ni) {
      const int colg = bn * 128 + wn * 64 + ni * 16 + laneN;
      const float bb = bias[colg];
      if (omode == 2) {
        // Vt [B,H,Hd,S]: r -> 4 consecutive s, same hd -> one b64 store
        const int rowg0 = bm * 128 + wm * 64 + mi * 16 + quad * 4;
        const int b = rowg0 >> 11, s0 = rowg0 & 2047;
        const int h = colg >> 6, hd = colg & 63;
        short pk[4];
#pragma unroll
        for (int r = 0; r < 4; ++r) pk[r] = f2h(acc[mi][ni][r] + bb);
        i32x2 w; __builtin_memcpy(&w, pk, 8);
        *(i32x2*)(Vt + (((size_t)(b * H_ + h)) * HD_ + hd) * S_ + s0) = w;
      } else {
#pragma unroll
        for (int r = 0; r < 4; ++r) {
          const int rowg = bm * 128 + wm * 64 + mi * 16 + quad * 4 + r;
          const int b = rowg >> 11, s = rowg & 2047;
          const int h = colg >> 6, hd = colg & 63;
          Out[(((size_t)(b * H_ + h)) * S_ + s) * HD_ + hd] =
              f2h((acc[mi][ni][r] + bb) * scale);
        }
      }
    }
}

// ---------------------------------------------------------------------------
// O projection: fp16 A x fp16 Wo -> fp32. Tile 128(M)x64(N), 4 waves each
// 64x32 (acc 4x2, 8 MFMA : 6 ds_read). Grid 512 (2 blocks/CU), XCD swizzle:
// bn = (blk&7)*2 + (g&1), bm = g>>1 -> Wo tiles stay L2-resident per XCD.
// ---------------------------------------------------------------------------
__global__ __launch_bounds__(256, 3)
void gemm_out(const short* __restrict__ Ap, const short* __restrict__ Wp,
              const float* __restrict__ bias, float* __restrict__ Out) {
  __shared__ short As[2 * 4096];   // 128x32
  __shared__ short Bs[2 * 2048];   // 64x32
  const int blk = blockIdx.x;
  const int g = blk >> 3;
  const int bn = (blk & 7) * 2 + (g & 1), bm = g >> 1;

  const int t = threadIdx.x, wave = t >> 6, lane = t & 63;
  const int laneN = lane & 15, quad = lane >> 4;
  const int wm = wave & 1, wn = wave >> 1;

  f32x4 acc[4][2];
#pragma unroll
  for (int i = 0; i < 4; ++i)
#pragma unroll
    for (int j = 0; j < 2; ++j)
#pragma unroll
      for (int r = 0; r < 4; ++r) acc[i][j][r] = 0.f;

  auto stage = [&](int buf, int kk) {
#pragma unroll
    for (int j = 0; j < 2; ++j) {
      const int chunk = j * 256 + t;
      const int row = chunk >> 2;
      const int gg = (chunk & 3) ^ ((row >> 1) & 3);
      async_copy16(Ap + (size_t)(bm * 128 + row) * KDIM + kk + gg * 8,
                   As + buf * 4096 + chunk * 8);
    }
    {
      const int chunk = t;
      const int row = chunk >> 2;
      const int gg = (chunk & 3) ^ ((row >> 1) & 3);
      async_copy16(Wp + (size_t)(bn * 64 + row) * KDIM + kk + gg * 8,
                   Bs + buf * 2048 + chunk * 8);
    }
  };

  stage(0, 0);
  int buf = 0;
  for (int kk = 0; kk < KDIM; kk += 32, buf ^= 1) {
    if (kk + 32 < KDIM) {
      stage(buf ^ 1, kk + 32);
      WAITCNT_VM(3);
    } else {
      WAITCNT_VM(0);
    }
    RAW_BARRIER();

    frag8 aF[4], bF[2];
#pragma unroll
    for (int mi = 0; mi < 4; ++mi) {
      const int row = wm * 64 + mi * 16 + laneN;
      aF[mi] = ld_frag(As + buf * 4096 + row * 32 +
                       ((quad ^ ((row >> 1) & 3)) * 8));
    }
#pragma unroll
    for (int ni = 0; ni < 2; ++ni) {
      const int row = wn * 32 + ni * 16 + laneN;
      bF[ni] = ld_frag(Bs + buf * 2048 + row * 32 +
                       ((quad ^ ((row >> 1) & 3)) * 8));
    }
#pragma unroll
    for (int mi = 0; mi < 4; ++mi)
#pragma unroll
      for (int ni = 0; ni < 2; ++ni)
        acc[mi][ni] = mfma_f16(aF[mi], bF[ni], acc[mi][ni]);
    RAW_BARRIER();
  }

#pragma unroll
  for (int mi = 0; mi < 4; ++mi)
#pragma unroll
    for (int ni = 0; ni < 2; ++ni) {
      const int colg = bn * 64 + wn * 32 + ni * 16 + laneN;
      const float bb = bias[colg];
#pragma unroll
      for (int r = 0; r < 4; ++r) {
        const int rowg = bm * 128 + wm * 64 + mi * 16 + quad * 4 + r;
        Out[(size_t)rowg * 1024 + colg] = acc[mi][ni][r] + bb;
      }
    }
}

// ---------------------------------------------------------------------------
// Flash attention, fp16, 256 threads = 4 waves x 2 q-sets x 16 = 128 q/block.
// K/Vt frags amortized over both sets. Transposed scores mfma(A=K,B=Q) ->
// S^T; in-lane softmax + xor16/xor32; wave-uniform __any skip of the
// alpha-rescale; PV mfma(A=Vt,B=P) -> O^T. Double-buffered async staging
// (vmcnt(0) peel), exp2-domain softmax (Q pre-scaled 8*log2e). XCD-aware
// grid. LDS 41.2KB.
// ---------------------------------------------------------------------------
__global__ __launch_bounds__(256, 2)
void attn(const short* __restrict__ Qf, const short* __restrict__ Kf,
          const short* __restrict__ Vt_, short* __restrict__ Ow) {
  __shared__ short Ks[2 * 4096];
  __shared__ short Vts[2 * 4096];
  __shared__ short Ps[4][16 * 72];  // per-wave strip [q][k], reused per set

  // XCD-locality: 512 blocks, 8 groups x 4 (h,b) pairs x 16 q-tiles
  const int blk = blockIdx.x;
  const int xcd = blk & 7, local = blk >> 3;
  const int pair = xcd * 4 + (local >> 4);
  const int h = pair & 15, b = pair >> 4, qt = local & 15;
  const size_t head = ((size_t)b * H_ + h) * (size_t)S_ * HD_;

  const int t = threadIdx.x;
  const int wave = t >> 6, lane = t & 63;
  const int laneN = lane & 15, quad = lane >> 4;

  // Q frags (B-operand); wave owns 2 sets of 16 q rows
  frag8 qf[2][2];
#pragma unroll
  for (int st = 0; st < 2; ++st) {
    const size_t row = (size_t)qt * 128 + wave * 32 + st * 16 + laneN;
#pragma unroll
    for (int half = 0; half < 2; ++half)
      qf[st][half] = ld_frag(Qf + head + row * HD_ + half * 32 + quad * 8);
  }

  f32x4 o[2][4];          // O^T per set: row d = dt*16+quad*4+r, col q=laneN
  float m_r[2] = { -1e30f, -1e30f }, l_r[2] = { 0.f, 0.f };
#pragma unroll
  for (int st = 0; st < 2; ++st)
#pragma unroll
    for (int i = 0; i < 4; ++i)
#pragma unroll
      for (int j = 0; j < 4; ++j) o[st][i][j] = 0.f;

  auto stage = [&](int buf, int kt) {
#pragma unroll
    for (int j = 0; j < 2; ++j) {
      const int chunk = j * 256 + t;      // 0..511
      const int row = chunk >> 3;         // 0..63
      const int g = (chunk & 7) ^ (row & 7);
      const int ldsoff = buf * 4096 + chunk * 8;
      async_copy16(Kf + head + (size_t)(kt * 64 + row) * HD_ + g * 8, Ks + ldsoff);
      async_copy16(Vt_ + head + (size_t)row * S_ + kt * 64 + g * 8, Vts + ldsoff);
    }
  };

  stage(0, 0);
  int buf = 0;
  for (int kt = 0; kt < 32; ++kt, buf ^= 1) {
    if (kt + 1 < 32) {
      stage(buf ^ 1, kt + 1);
      WAITCNT_VM(4);
    } else {
      WAITCNT_VM(0);
    }
    RAW_BARRIER();

    // Vt frags (A-operand of PV), shared by both sets
    frag8 vf[4][2];
#pragma unroll
    for (int dt = 0; dt < 4; ++dt) {
      const int row = dt * 16 + laneN;
#pragma unroll
      for (int half = 0; half < 2; ++half)
        vf[dt][half] = ld_frag(Vts + buf * 4096 + row * 64 +
                               (((half * 4 + quad) ^ (row & 7)) * 8));
    }

    // S^T = K.Q^T for both sets (K frags loaded once)
    f32x4 s[2][4];
#pragma unroll
    for (int nt = 0; nt < 4; ++nt) {
      const int row = nt * 16 + laneN;
      const int o0 = buf * 4096 + row * 64 + ((quad ^ (row & 7)) * 8);
      const int o1 = buf * 4096 + row * 64 + (((quad + 4) ^ (row & 7)) * 8);
      frag8 k0 = ld_frag(Ks + o0), k1 = ld_frag(Ks + o1);
#pragma unroll
      for (int st = 0; st < 2; ++st) {
        f32x4 acc;
#pragma unroll
        for (int j = 0; j < 4; ++j) acc[j] = 0.f;
        acc = mfma_f16(k0, qf[st][0], acc);
        acc = mfma_f16(k1, qf[st][1], acc);
        s[st][nt] = acc;
      }
    }

#pragma unroll
    for (int st = 0; st < 2; ++st) {
      // online softmax (exp2 domain): in-lane 16 + xor16/xor32
      float mx = -1e30f;
#pragma unroll
      for (int nt = 0; nt < 4; ++nt)
#pragma unroll
        for (int r = 0; r < 4; ++r) mx = fmaxf(mx, s[st][nt][r]);
      mx = fmaxf(mx, __shfl_xor(mx, 16));
      mx = fmaxf(mx, __shfl_xor(mx, 32));
      const float mold = m_r[st];
      const float mn = fmaxf(mold, mx);
      float rs = 0.f;
#pragma unroll
      for (int nt = 0; nt < 4; ++nt)
#pragma unroll
        for (int r = 0; r < 4; ++r) {
          const float p = fast_exp2(s[st][nt][r] - mn);
          s[st][nt][r] = p; rs += p;
        }
      rs += __shfl_xor(rs, 16);
      rs += __shfl_xor(rs, 32);
      if (__any(mn > mold)) {      // wave-uniform: rescale only if max grew
        const float al = fast_exp2(mold - mn);
        m_r[st] = mn;
        l_r[st] = l_r[st] * al + rs;
#pragma unroll
        for (int dt = 0; dt < 4; ++dt)
#pragma unroll
          for (int r = 0; r < 4; ++r) o[st][dt][r] *= al;
      } else {
        l_r[st] += rs;
      }

      // P pack: 4 consecutive k per nt -> one b64 write; strip [q][k]
#pragma unroll
      for (int nt = 0; nt < 4; ++nt) {
        i32x2 w;
        w[0] = pk2h(s[st][nt][0], s[st][nt][1]);
        w[1] = pk2h(s[st][nt][2], s[st][nt][3]);
        *(i32x2*)&Ps[wave][laneN * 72 + nt * 16 + quad * 4] = w;
      }
      const frag8 p0 = ld_frag(&Ps[wave][laneN * 72 + quad * 8]);
      const frag8 p1 = ld_frag(&Ps[wave][laneN * 72 + 32 + quad * 8]);
#pragma unroll
      for (int dt = 0; dt < 4; ++dt) {
        o[st][dt] = mfma_f16(vf[dt][0], p0, o[st][dt]);
        o[st][dt] = mfma_f16(vf[dt][1], p1, o[st][dt]);
      }
    }
    RAW_BARRIER();
  }

  // epilogue: O^T -> Ow[B,S,D] fp16; lane owns q, 4 consecutive d per dt
#pragma unroll
  for (int st = 0; st < 2; ++st) {
    const float inv = 1.0f / l_r[st];
    const int sg = qt * 128 + wave * 32 + st * 16 + laneN;
    short* dst = Ow + ((size_t)b * S_ + sg) * D_ + h * HD_;
#pragma unroll
    for (int dt = 0; dt < 4; ++dt) {
      short pk[4] = { f2h(o[st][dt][0] * inv), f2h(o[st][dt][1] * inv),
                      f2h(o[st][dt][2] * inv), f2h(o[st][dt][3] * inv) };
      i32x2 w; __builtin_memcpy(&w, pk, 8);
      *(i32x2*)(dst + dt * 16 + quad * 4) = w;
    }
  }
}

// ---------------------------------------------------------------------------
extern "C" void kernel_launch(void* const* d_in, const int* in_sizes, int n_in,
                              void* d_out, int out_size, void* d_ws, size_t ws_size,
                              hipStream_t stream) {
  const float* q  = (const float*)d_in[0];
  const float* k  = (const float*)d_in[1];
  const float* v  = (const float*)d_in[2];
  const float* Wq = (const float*)d_in[3];
  const float* bq = (const float*)d_in[4];
  const float* Wk = (const float*)d_in[5];
  const float* bk = (const float*)d_in[6];
  const float* Wv = (const float*)d_in[7];
  const float* bv = (const float*)d_in[8];
  const float* Wo = (const float*)d_in[9];
  const float* bo = (const float*)d_in[10];

  const size_t NTOK = (size_t)B_ * S_ * D_;   // 4,194,304
  const size_t NW   = (size_t)D_ * D_;        // 1,048,576
  short* p = (short*)d_ws;
  short* qh = p; p += NTOK;  short* kh = p; p += NTOK;  short* vh = p; p += NTOK;
  short* wq = p; p += NW;    short* wk = p; p += NW;
  short* wv = p; p += NW;    short* wo = p; p += NW;
  short* Qf = p; p += NTOK;  short* Kf = p; p += NTOK;
  short* Vt = p; p += NTOK;  short* Ow = p; p += NTOK;

  dim3 blk(256);

  conv_all<<<8192, blk, 0, stream>>>(q, k, v, Wq, Wk, Wv, Wo,
                                     qh, kh, vh, wq, wk, wv, wo);

  const float QS = 11.541560327111707f;  // 8 * log2(e): exp2-domain softmax
  gemm_qkv<<<768, blk, 0, stream>>>(qh, kh, vh, wq, wk, wv, bq, bk, bv,
                                    Qf, Kf, Vt, QS);

  attn<<<512, blk, 0, stream>>>(Qf, Kf, Vt, Ow);

  gemm_out<<<512, blk, 0, stream>>>(Ow, wo, bo, (float*)d_out);
}

// Round 11
// 227.676 us; speedup vs baseline: 1.0830x; 1.0165x over previous
//
#include <hip/hip_runtime.h>
#include <type_traits>
#include <utility>

#define B_ 2
#define S_ 2048
#define D_ 1024
#define H_ 16
#define HD_ 64
#define KDIM 1024

typedef __attribute__((ext_vector_type(8))) short    s16x8;
typedef __attribute__((ext_vector_type(8))) _Float16 h16x8;
typedef __attribute__((ext_vector_type(4))) float    f32x4;
typedef __attribute__((ext_vector_type(4))) int      i32x4;
typedef __attribute__((ext_vector_type(2))) int      i32x2;

// --- MFMA operand-type hedge (fp16) ---
template <typename T, typename = void> struct mfma_takes : std::false_type {};
template <typename T>
struct mfma_takes<T, std::void_t<decltype(__builtin_amdgcn_mfma_f32_16x16x32_f16(
    std::declval<T>(), std::declval<T>(), std::declval<f32x4>(), 0, 0, 0))>>
    : std::true_type {};
using frag8 = std::conditional_t<mfma_takes<h16x8>::value, h16x8, s16x8>;

__device__ __forceinline__ f32x4 mfma_f16(frag8 a, frag8 b, f32x4 c) {
  return __builtin_amdgcn_mfma_f32_16x16x32_f16(a, b, c, 0, 0, 0);
}

__device__ __forceinline__ short f2h(float f) {  // RTNE f32 -> fp16 bits
  _Float16 h = (_Float16)f;
  short s; __builtin_memcpy(&s, &h, 2);
  return s;
}
__device__ __forceinline__ int pk2h(float a, float b) {  // v_cvt_pkrtz 2xfp16
  auto p = __builtin_amdgcn_cvt_pkrtz(a, b);   // __fp16 ext_vector(2)
  int r; __builtin_memcpy(&r, &p, 4); return r;
}
__device__ __forceinline__ frag8 ld_frag(const short* p) {
  return __builtin_bit_cast(frag8, *(const i32x4*)p);
}
__device__ __forceinline__ float fast_exp2(float x) {
  return __builtin_amdgcn_exp2f(x);
}

typedef __attribute__((address_space(1))) const void gvoid;
typedef __attribute__((address_space(3))) void lvoid;
__device__ __forceinline__ void async_copy16(const void* g, void* l) {
  __builtin_amdgcn_global_load_lds((gvoid*)g, (lvoid*)l, 16, 0, 0);
}

#define RAW_BARRIER() asm volatile("s_barrier" ::: "memory")
#define WAITCNT_VM(n) asm volatile("s_waitcnt vmcnt(" #n ")" ::: "memory")

// ---------------------------------------------------------------------------
// Fused fp32 -> fp16 converts: q,k,v (2048 blocks each) + 4 weights (512 each)
// ---------------------------------------------------------------------------
__global__ __launch_bounds__(256)
void conv_all(const float* __restrict__ q, const float* __restrict__ k,
              const float* __restrict__ v, const float* __restrict__ Wq,
              const float* __restrict__ Wk, const float* __restrict__ Wv,
              const float* __restrict__ Wo,
              short* __restrict__ qh, short* __restrict__ kh,
              short* __restrict__ vh, short* __restrict__ wq,
              short* __restrict__ wk, short* __restrict__ wv,
              short* __restrict__ wo) {
  const int blk = blockIdx.x;
  const float* src; short* dst; int base;
  if (blk < 2048)      { src = q;  dst = qh; base = blk; }
  else if (blk < 4096) { src = k;  dst = kh; base = blk - 2048; }
  else if (blk < 6144) { src = v;  dst = vh; base = blk - 4096; }
  else if (blk < 6656) { src = Wq; dst = wq; base = blk - 6144; }
  else if (blk < 7168) { src = Wk; dst = wk; base = blk - 6656; }
  else if (blk < 7680) { src = Wv; dst = wv; base = blk - 7168; }
  else                 { src = Wo; dst = wo; base = blk - 7680; }
  const int i = base * 2048 + threadIdx.x * 8;
  float4 a0 = *(const float4*)(src + i);
  float4 a1 = *(const float4*)(src + i + 4);
  short h[8] = { f2h(a0.x), f2h(a0.y), f2h(a0.z), f2h(a0.w),
                 f2h(a1.x), f2h(a1.y), f2h(a1.z), f2h(a1.w) };
  i32x4 ph; __builtin_memcpy(&ph, h, 16);
  *(i32x4*)(dst + i) = ph;
}

// ---------------------------------------------------------------------------
// QKV projection GEMM, fp16 A & W, tile 128x128, BK=32. TRIPLE-buffered
// global_load_lds staging with prefetch distance 2 (per-iter compute ~300cyc
// < load latency ~500-900cyc, so distance-1 stalled every iter). XCD-aware
// 1-D grid (768): bn = blk&7 -> W column tile L2-resident per XCD.
// LDS 48KB -> 3 blocks/CU.
// ---------------------------------------------------------------------------
__global__ __launch_bounds__(256, 3)
void gemm_qkv(const short* __restrict__ qh, const short* __restrict__ kh,
              const short* __restrict__ vh, const short* __restrict__ wq,
              const short* __restrict__ wk, const short* __restrict__ wv,
              const float* __restrict__ bq, const float* __restrict__ bk,
              const float* __restrict__ bv, short* __restrict__ Qf,
              short* __restrict__ Kf, short* __restrict__ Vt, float QS) {
  __shared__ short As[3 * 4096];
  __shared__ short Bs[3 * 4096];

  const int blk = blockIdx.x;
  const int bn = blk & 7, g = blk >> 3;
  const int z = g >> 5, bm = g & 31;
  const short* Ap = z == 0 ? qh : z == 1 ? kh : vh;
  const short* Wp = z == 0 ? wq : z == 1 ? wk : wv;
  const float* bias = z == 0 ? bq : z == 1 ? bk : bv;
  short* Out = z == 0 ? Qf : z == 1 ? Kf : Vt;
  const float scale = z == 0 ? QS : 1.0f;
  const int omode = z == 2 ? 2 : 1;

  const int t = threadIdx.x, wave = t >> 6, lane = t & 63;
  const int laneN = lane & 15, quad = lane >> 4;
  const int wm = wave & 1, wn = wave >> 1;

  f32x4 acc[4][4];
#pragma unroll
  for (int i = 0; i < 4; ++i)
#pragma unroll
    for (int j = 0; j < 4; ++j)
#pragma unroll
      for (int r = 0; r < 4; ++r) acc[i][j][r] = 0.f;

  auto stage = [&](int buf, int kk) {   // 4 asyncs/thread per call
#pragma unroll
    for (int j = 0; j < 2; ++j) {
      const int chunk = j * 256 + t;
      const int row = chunk >> 2;
      const int gg = (chunk & 3) ^ ((row >> 1) & 3);
      async_copy16(Ap + (size_t)(bm * 128 + row) * KDIM + kk + gg * 8,
                   As + buf * 4096 + chunk * 8);
      async_copy16(Wp + (size_t)(bn * 128 + row) * KDIM + kk + gg * 8,
                   Bs + buf * 4096 + chunk * 8);
    }
  };

  stage(0, 0);
  stage(1, 32);
  int buf = 0;
  for (int kk = 0; kk < KDIM; kk += 32) {
    if (kk + 64 < KDIM) {
      int nb = buf + 2; if (nb >= 3) nb -= 3;
      stage(nb, kk + 64);
      WAITCNT_VM(8);        // drain current tile (oldest 4 of 12)
    } else if (kk + 32 < KDIM) {
      WAITCNT_VM(4);
    } else {
      WAITCNT_VM(0);
    }
    RAW_BARRIER();

    frag8 aF[4], bF[4];
#pragma unroll
    for (int mi = 0; mi < 4; ++mi) {
      const int row = wm * 64 + mi * 16 + laneN;
      aF[mi] = ld_frag(As + buf * 4096 + row * 32 +
                       ((quad ^ ((row >> 1) & 3)) * 8));
    }
#pragma unroll
    for (int ni = 0; ni < 4; ++ni) {
      const int row = wn * 64 + ni * 16 + laneN;
      bF[ni] = ld_frag(Bs + buf * 4096 + row * 32 +
                       ((quad ^ ((row >> 1) & 3)) * 8));
    }
#pragma unroll
    for (int mi = 0; mi < 4; ++mi)
#pragma unroll
      for (int ni = 0; ni < 4; ++ni)
        acc[mi][ni] = mfma_f16(aF[mi], bF[ni], acc[mi][ni]);
    RAW_BARRIER();
    buf = buf + 1 == 3 ? 0 : buf + 1;
  }

  // Epilogue. C/D: col = lane&15, row = quad*4 + reg.
#pragma unroll
  for (int mi = 0; mi < 4; ++mi)
#pragma unroll
    for (int ni = 0; ni < 4; ++ni) {
      const int colg = bn * 128 + wn * 64 + ni * 16 + laneN;
      const float bb = bias[colg];
      if (omode == 2) {
        // Vt [B,H,Hd,S]: r -> 4 consecutive s, same hd -> one b64 store
        const int rowg0 = bm * 128 + wm * 64 + mi * 16 + quad * 4;
        const int b = rowg0 >> 11, s0 = rowg0 & 2047;
        const int h = colg >> 6, hd = colg & 63;
        short pk[4];
#pragma unroll
        for (int r = 0; r < 4; ++r) pk[r] = f2h(acc[mi][ni][r] + bb);
        i32x2 w; __builtin_memcpy(&w, pk, 8);
        *(i32x2*)(Vt + (((size_t)(b * H_ + h)) * HD_ + hd) * S_ + s0) = w;
      } else {
#pragma unroll
        for (int r = 0; r < 4; ++r) {
          const int rowg = bm * 128 + wm * 64 + mi * 16 + quad * 4 + r;
          const int b = rowg >> 11, s = rowg & 2047;
          const int h = colg >> 6, hd = colg & 63;
          Out[(((size_t)(b * H_ + h)) * S_ + s) * HD_ + hd] =
              f2h((acc[mi][ni][r] + bb) * scale);
        }
      }
    }
}

// ---------------------------------------------------------------------------
// O projection: fp16 A x fp16 Wo -> fp32. Tile 128(M)x64(N), triple-buffered
// prefetch distance 2 (3 asyncs/stage). Grid 512, XCD swizzle. LDS 36KB.
// ---------------------------------------------------------------------------
__global__ __launch_bounds__(256, 3)
void gemm_out(const short* __restrict__ Ap, const short* __restrict__ Wp,
              const float* __restrict__ bias, float* __restrict__ Out) {
  __shared__ short As[3 * 4096];   // 128x32
  __shared__ short Bs[3 * 2048];   // 64x32
  const int blk = blockIdx.x;
  const int g = blk >> 3;
  const int bn = (blk & 7) * 2 + (g & 1), bm = g >> 1;

  const int t = threadIdx.x, wave = t >> 6, lane = t & 63;
  const int laneN = lane & 15, quad = lane >> 4;
  const int wm = wave & 1, wn = wave >> 1;

  f32x4 acc[4][2];
#pragma unroll
  for (int i = 0; i < 4; ++i)
#pragma unroll
    for (int j = 0; j < 2; ++j)
#pragma unroll
      for (int r = 0; r < 4; ++r) acc[i][j][r] = 0.f;

  auto stage = [&](int buf, int kk) {   // 3 asyncs/thread per call
#pragma unroll
    for (int j = 0; j < 2; ++j) {
      const int chunk = j * 256 + t;
      const int row = chunk >> 2;
      const int gg = (chunk & 3) ^ ((row >> 1) & 3);
      async_copy16(Ap + (size_t)(bm * 128 + row) * KDIM + kk + gg * 8,
                   As + buf * 4096 + chunk * 8);
    }
    {
      const int chunk = t;
      const int row = chunk >> 2;
      const int gg = (chunk & 3) ^ ((row >> 1) & 3);
      async_copy16(Wp + (size_t)(bn * 64 + row) * KDIM + kk + gg * 8,
                   Bs + buf * 2048 + chunk * 8);
    }
  };

  stage(0, 0);
  stage(1, 32);
  int buf = 0;
  for (int kk = 0; kk < KDIM; kk += 32) {
    if (kk + 64 < KDIM) {
      int nb = buf + 2; if (nb >= 3) nb -= 3;
      stage(nb, kk + 64);
      WAITCNT_VM(6);
    } else if (kk + 32 < KDIM) {
      WAITCNT_VM(3);
    } else {
      WAITCNT_VM(0);
    }
    RAW_BARRIER();

    frag8 aF[4], bF[2];
#pragma unroll
    for (int mi = 0; mi < 4; ++mi) {
      const int row = wm * 64 + mi * 16 + laneN;
      aF[mi] = ld_frag(As + buf * 4096 + row * 32 +
                       ((quad ^ ((row >> 1) & 3)) * 8));
    }
#pragma unroll
    for (int ni = 0; ni < 2; ++ni) {
      const int row = wn * 32 + ni * 16 + laneN;
      bF[ni] = ld_frag(Bs + buf * 2048 + row * 32 +
                       ((quad ^ ((row >> 1) & 3)) * 8));
    }
#pragma unroll
    for (int mi = 0; mi < 4; ++mi)
#pragma unroll
      for (int ni = 0; ni < 2; ++ni)
        acc[mi][ni] = mfma_f16(aF[mi], bF[ni], acc[mi][ni]);
    RAW_BARRIER();
    buf = buf + 1 == 3 ? 0 : buf + 1;
  }

#pragma unroll
  for (int mi = 0; mi < 4; ++mi)
#pragma unroll
    for (int ni = 0; ni < 2; ++ni) {
      const int colg = bn * 64 + wn * 32 + ni * 16 + laneN;
      const float bb = bias[colg];
#pragma unroll
      for (int r = 0; r < 4; ++r) {
        const int rowg = bm * 128 + wm * 64 + mi * 16 + quad * 4 + r;
        Out[(size_t)rowg * 1024 + colg] = acc[mi][ni][r] + bb;
      }
    }
}

// ---------------------------------------------------------------------------
// Flash attention, fp16, 512 threads = 8 waves x 16 q = 128 q/block
// (16 waves/CU — the measured-best occupancy config, R7=64.6us). Keeps the
// R10 wins: XCD-aware grid (attn FETCH 69.7->12.3MB measured), __any
// rescale-skip, pk2h P-pack. Transposed scores mfma(A=K,B=Q) -> S^T;
// in-lane softmax + xor16/xor32; PV mfma(A=Vt,B=P) -> O^T. Double-buffered
// async staging (iter compute ~800cyc covers latency at distance 1).
// LDS 50KB -> 2 blocks/CU.
// ---------------------------------------------------------------------------
__global__ __launch_bounds__(512, 2)
void attn(const short* __restrict__ Qf, const short* __restrict__ Kf,
          const short* __restrict__ Vt_, short* __restrict__ Ow) {
  __shared__ short Ks[2 * 4096];
  __shared__ short Vts[2 * 4096];
  __shared__ short Ps[8][16 * 72];  // per-wave P strip [q][k], stride 72

  // XCD-locality: 512 blocks, 8 groups x 4 (h,b) pairs x 16 q-tiles
  const int blk = blockIdx.x;
  const int xcd = blk & 7, local = blk >> 3;
  const int pair = xcd * 4 + (local >> 4);
  const int h = pair & 15, b = pair >> 4, qt = local & 15;
  const size_t head = ((size_t)b * H_ + h) * (size_t)S_ * HD_;

  const int t = threadIdx.x;
  const int wave = t >> 6, lane = t & 63;
  const int laneN = lane & 15, quad = lane >> 4;

  // Q frags (B-operand); wave owns 16 q rows
  frag8 qf[2];
  {
    const size_t row = (size_t)qt * 128 + wave * 16 + laneN;
#pragma unroll
    for (int half = 0; half < 2; ++half)
      qf[half] = ld_frag(Qf + head + row * HD_ + half * 32 + quad * 8);
  }

  f32x4 o[4];          // O^T: row d = dt*16+quad*4+r, col q = laneN
  float m_r = -1e30f, l_r = 0.f;
#pragma unroll
  for (int i = 0; i < 4; ++i)
#pragma unroll
    for (int j = 0; j < 4; ++j) o[i][j] = 0.f;

  auto stage = [&](int buf, int kt) {   // 2 asyncs/thread
    const int chunk = t;                // 0..511
    const int row = chunk >> 3;         // 0..63
    const int g = (chunk & 7) ^ (row & 7);
    const int ldsoff = buf * 4096 + chunk * 8;
    async_copy16(Kf + head + (size_t)(kt * 64 + row) * HD_ + g * 8, Ks + ldsoff);
    async_copy16(Vt_ + head + (size_t)row * S_ + kt * 64 + g * 8, Vts + ldsoff);
  };

  stage(0, 0);
  int buf = 0;
  for (int kt = 0; kt < 32; ++kt, buf ^= 1) {
    if (kt + 1 < 32) {
      stage(buf ^ 1, kt + 1);
      WAITCNT_VM(2);
    } else {
      WAITCNT_VM(0);
    }
    RAW_BARRIER();

    // Vt frags (A-operand of PV): rows d = dt*16+laneN
    frag8 vf[4][2];
#pragma unroll
    for (int dt = 0; dt < 4; ++dt) {
      const int row = dt * 16 + laneN;
#pragma unroll
      for (int half = 0; half < 2; ++half)
        vf[dt][half] = ld_frag(Vts + buf * 4096 + row * 64 +
                               (((half * 4 + quad) ^ (row & 7)) * 8));
    }

    // S^T = K.Q^T: per lane 16 logits for q=laneN, k = nt*16+quad*4+r
    f32x4 s[4];
#pragma unroll
    for (int nt = 0; nt < 4; ++nt) {
      const int row = nt * 16 + laneN;
      const int o0 = buf * 4096 + row * 64 + ((quad ^ (row & 7)) * 8);
      const int o1 = buf * 4096 + row * 64 + (((quad + 4) ^ (row & 7)) * 8);
      frag8 k0 = ld_frag(Ks + o0), k1 = ld_frag(Ks + o1);
      f32x4 acc;
#pragma unroll
      for (int j = 0; j < 4; ++j) acc[j] = 0.f;
      acc = mfma_f16(k0, qf[0], acc);
      acc = mfma_f16(k1, qf[1], acc);
      s[nt] = acc;
    }

    // online softmax (exp2 domain): in-lane reduce 16 + xor16/xor32
    {
      float mx = -1e30f;
#pragma unroll
      for (int nt = 0; nt < 4; ++nt)
#pragma unroll
        for (int r = 0; r < 4; ++r) mx = fmaxf(mx, s[nt][r]);
      mx = fmaxf(mx, __shfl_xor(mx, 16));
      mx = fmaxf(mx, __shfl_xor(mx, 32));
      const float mold = m_r;
      const float mn = fmaxf(mold, mx);
      float rs = 0.f;
#pragma unroll
      for (int nt = 0; nt < 4; ++nt)
#pragma unroll
        for (int r = 0; r < 4; ++r) {
          const float p = fast_exp2(s[nt][r] - mn);
          s[nt][r] = p; rs += p;
        }
      rs += __shfl_xor(rs, 16);
      rs += __shfl_xor(rs, 32);
      if (__any(mn > mold)) {      // wave-uniform: rescale only if max grew
        const float al = fast_exp2(mold - mn);
        m_r = mn;
        l_r = l_r * al + rs;
#pragma unroll
        for (int dt = 0; dt < 4; ++dt)
#pragma unroll
          for (int r = 0; r < 4; ++r) o[dt][r] *= al;
      } else {
        l_r += rs;
      }
    }

    // P pack: 4 consecutive k per nt -> one b64 LDS write; strip [q][k]
#pragma unroll
    for (int nt = 0; nt < 4; ++nt) {
      i32x2 w;
      w[0] = pk2h(s[nt][0], s[nt][1]);
      w[1] = pk2h(s[nt][2], s[nt][3]);
      *(i32x2*)&Ps[wave][laneN * 72 + nt * 16 + quad * 4] = w;
    }
    // B-operand P frags (per-wave strip; in-order DS within a wave)
    const frag8 p0 = ld_frag(&Ps[wave][laneN * 72 + quad * 8]);
    const frag8 p1 = ld_frag(&Ps[wave][laneN * 72 + 32 + quad * 8]);
#pragma unroll
    for (int dt = 0; dt < 4; ++dt) {
      o[dt] = mfma_f16(vf[dt][0], p0, o[dt]);
      o[dt] = mfma_f16(vf[dt][1], p1, o[dt]);
    }
    RAW_BARRIER();
  }

  // epilogue: O^T -> Ow[B,S,D] fp16; lane owns q, 4 consecutive d per dt
  {
    const float inv = 1.0f / l_r;
    const int sg = qt * 128 + wave * 16 + laneN;
    short* dst = Ow + ((size_t)b * S_ + sg) * D_ + h * HD_;
#pragma unroll
    for (int dt = 0; dt < 4; ++dt) {
      short pk[4] = { f2h(o[dt][0] * inv), f2h(o[dt][1] * inv),
                      f2h(o[dt][2] * inv), f2h(o[dt][3] * inv) };
      i32x2 w; __builtin_memcpy(&w, pk, 8);
      *(i32x2*)(dst + dt * 16 + quad * 4) = w;
    }
  }
}

// ---------------------------------------------------------------------------
extern "C" void kernel_launch(void* const* d_in, const int* in_sizes, int n_in,
                              void* d_out, int out_size, void* d_ws, size_t ws_size,
                              hipStream_t stream) {
  const float* q  = (const float*)d_in[0];
  const float* k  = (const float*)d_in[1];
  const float* v  = (const float*)d_in[2];
  const float* Wq = (const float*)d_in[3];
  const float* bq = (const float*)d_in[4];
  const float* Wk = (const float*)d_in[5];
  const float* bk = (const float*)d_in[6];
  const float* Wv = (const float*)d_in[7];
  const float* bv = (const float*)d_in[8];
  const float* Wo = (const float*)d_in[9];
  const float* bo = (const float*)d_in[10];

  const size_t NTOK = (size_t)B_ * S_ * D_;   // 4,194,304
  const size_t NW   = (size_t)D_ * D_;        // 1,048,576
  short* p = (short*)d_ws;
  short* qh = p; p += NTOK;  short* kh = p; p += NTOK;  short* vh = p; p += NTOK;
  short* wq = p; p += NW;    short* wk = p; p += NW;
  short* wv = p; p += NW;    short* wo = p; p += NW;
  short* Qf = p; p += NTOK;  short* Kf = p; p += NTOK;
  short* Vt = p; p += NTOK;  short* Ow = p; p += NTOK;

  dim3 blk(256);

  conv_all<<<8192, blk, 0, stream>>>(q, k, v, Wq, Wk, Wv, Wo,
                                     qh, kh, vh, wq, wk, wv, wo);

  const float QS = 11.541560327111707f;  // 8 * log2(e): exp2-domain softmax
  gemm_qkv<<<768, blk, 0, stream>>>(qh, kh, vh, wq, wk, wv, bq, bk, bv,
                                    Qf, Kf, Vt, QS);

  attn<<<512, dim3(512), 0, stream>>>(Qf, Kf, Vt, Ow);

  gemm_out<<<512, blk, 0, stream>>>(Ow, wo, bo, (float*)d_out);
}

// Round 12
// 223.002 us; speedup vs baseline: 1.1057x; 1.0210x over previous
//
#include <hip/hip_runtime.h>
#include <type_traits>
#include <utility>

#define B_ 2
#define S_ 2048
#define D_ 1024
#define H_ 16
#define HD_ 64
#define KDIM 1024

typedef __attribute__((ext_vector_type(8))) short    s16x8;
typedef __attribute__((ext_vector_type(8))) _Float16 h16x8;
typedef __attribute__((ext_vector_type(4))) float    f32x4;
typedef __attribute__((ext_vector_type(4))) int      i32x4;
typedef __attribute__((ext_vector_type(2))) int      i32x2;

// --- MFMA operand-type hedge (fp16) ---
template <typename T, typename = void> struct mfma_takes : std::false_type {};
template <typename T>
struct mfma_takes<T, std::void_t<decltype(__builtin_amdgcn_mfma_f32_16x16x32_f16(
    std::declval<T>(), std::declval<T>(), std::declval<f32x4>(), 0, 0, 0))>>
    : std::true_type {};
using frag8 = std::conditional_t<mfma_takes<h16x8>::value, h16x8, s16x8>;

__device__ __forceinline__ f32x4 mfma_f16(frag8 a, frag8 b, f32x4 c) {
  return __builtin_amdgcn_mfma_f32_16x16x32_f16(a, b, c, 0, 0, 0);
}

__device__ __forceinline__ short f2h(float f) {  // RTNE f32 -> fp16 bits
  _Float16 h = (_Float16)f;
  short s; __builtin_memcpy(&s, &h, 2);
  return s;
}
__device__ __forceinline__ int pk2h(float a, float b) {  // v_cvt_pkrtz 2xfp16
  auto p = __builtin_amdgcn_cvt_pkrtz(a, b);   // __fp16 ext_vector(2)
  int r; __builtin_memcpy(&r, &p, 4); return r;
}
__device__ __forceinline__ frag8 ld_frag(const short* p) {
  return __builtin_bit_cast(frag8, *(const i32x4*)p);
}
__device__ __forceinline__ float fast_exp2(float x) {
  return __builtin_amdgcn_exp2f(x);
}

typedef __attribute__((address_space(1))) const void gvoid;
typedef __attribute__((address_space(3))) void lvoid;
__device__ __forceinline__ void async_copy16(const void* g, void* l) {
  __builtin_amdgcn_global_load_lds((gvoid*)g, (lvoid*)l, 16, 0, 0);
}

#define RAW_BARRIER() asm volatile("s_barrier" ::: "memory")
#define WAITCNT_VM(n) asm volatile("s_waitcnt vmcnt(" #n ")" ::: "memory")

// ---------------------------------------------------------------------------
// Fused fp32 -> fp16 converts: q,k,v (2048 blocks each) + 4 weights (512 each)
// ---------------------------------------------------------------------------
__global__ __launch_bounds__(256)
void conv_all(const float* __restrict__ q, const float* __restrict__ k,
              const float* __restrict__ v, const float* __restrict__ Wq,
              const float* __restrict__ Wk, const float* __restrict__ Wv,
              const float* __restrict__ Wo,
              short* __restrict__ qh, short* __restrict__ kh,
              short* __restrict__ vh, short* __restrict__ wq,
              short* __restrict__ wk, short* __restrict__ wv,
              short* __restrict__ wo) {
  const int blk = blockIdx.x;
  const float* src; short* dst; int base;
  if (blk < 2048)      { src = q;  dst = qh; base = blk; }
  else if (blk < 4096) { src = k;  dst = kh; base = blk - 2048; }
  else if (blk < 6144) { src = v;  dst = vh; base = blk - 4096; }
  else if (blk < 6656) { src = Wq; dst = wq; base = blk - 6144; }
  else if (blk < 7168) { src = Wk; dst = wk; base = blk - 6656; }
  else if (blk < 7680) { src = Wv; dst = wv; base = blk - 7168; }
  else                 { src = Wo; dst = wo; base = blk - 7680; }
  const int i = base * 2048 + threadIdx.x * 8;
  float4 a0 = *(const float4*)(src + i);
  float4 a1 = *(const float4*)(src + i + 4);
  short h[8] = { f2h(a0.x), f2h(a0.y), f2h(a0.z), f2h(a0.w),
                 f2h(a1.x), f2h(a1.y), f2h(a1.z), f2h(a1.w) };
  i32x4 ph; __builtin_memcpy(&ph, h, 16);
  *(i32x4*)(dst + i) = ph;
}

// ---------------------------------------------------------------------------
// QKV projection GEMM, fp16 A & W, tile 128x128, BK=32, triple-buffered
// global_load_lds (prefetch distance 2). A-GROUPED XCD DECODE: all 8 bn
// blocks sharing one A-tile (z,bm) land on the same XCD (xcd = p&7 via
// p=(i>>3)*8+xcd), so each A tile is L2-filled once (24 MB total, was 192 MB
// with bn=blk&7 — R8 measured 200 MB FETCH at 3.4 TB/s = L3-BW-bound).
// z ascends with j so W_z (2 MB < 4 MB L2) streams once per XCD.
// ---------------------------------------------------------------------------
__global__ __launch_bounds__(256, 3)
void gemm_qkv(const short* __restrict__ qh, const short* __restrict__ kh,
              const short* __restrict__ vh, const short* __restrict__ wq,
              const short* __restrict__ wk, const short* __restrict__ wv,
              const float* __restrict__ bq, const float* __restrict__ bk,
              const float* __restrict__ bv, short* __restrict__ Qf,
              short* __restrict__ Kf, short* __restrict__ Vt, float QS) {
  __shared__ short As[3 * 4096];
  __shared__ short Bs[3 * 4096];

  const int blk = blockIdx.x;
  const int xcd = blk & 7, i = blk >> 3;      // i in [0,96)
  const int p = (i >> 3) * 8 + xcd;           // A-tile id, p ≡ xcd (mod 8)
  const int bn = i & 7;
  const int z = p >> 5, bm = p & 31;
  const short* Ap = z == 0 ? qh : z == 1 ? kh : vh;
  const short* Wp = z == 0 ? wq : z == 1 ? wk : wv;
  const float* bias = z == 0 ? bq : z == 1 ? bk : bv;
  short* Out = z == 0 ? Qf : z == 1 ? Kf : Vt;
  const float scale = z == 0 ? QS : 1.0f;
  const int omode = z == 2 ? 2 : 1;

  const int t = threadIdx.x, wave = t >> 6, lane = t & 63;
  const int laneN = lane & 15, quad = lane >> 4;
  const int wm = wave & 1, wn = wave >> 1;

  f32x4 acc[4][4];
#pragma unroll
  for (int i2 = 0; i2 < 4; ++i2)
#pragma unroll
    for (int j = 0; j < 4; ++j)
#pragma unroll
      for (int r = 0; r < 4; ++r) acc[i2][j][r] = 0.f;

  auto stage = [&](int buf, int kk) {   // 4 asyncs/thread per call
#pragma unroll
    for (int j = 0; j < 2; ++j) {
      const int chunk = j * 256 + t;
      const int row = chunk >> 2;
      const int gg = (chunk & 3) ^ ((row >> 1) & 3);
      async_copy16(Ap + (size_t)(bm * 128 + row) * KDIM + kk + gg * 8,
                   As + buf * 4096 + chunk * 8);
      async_copy16(Wp + (size_t)(bn * 128 + row) * KDIM + kk + gg * 8,
                   Bs + buf * 4096 + chunk * 8);
    }
  };

  stage(0, 0);
  stage(1, 32);
  int buf = 0;
  for (int kk = 0; kk < KDIM; kk += 32) {
    if (kk + 64 < KDIM) {
      int nb = buf + 2; if (nb >= 3) nb -= 3;
      stage(nb, kk + 64);
      WAITCNT_VM(8);        // drain current tile (oldest 4 of 12)
    } else if (kk + 32 < KDIM) {
      WAITCNT_VM(4);
    } else {
      WAITCNT_VM(0);
    }
    RAW_BARRIER();

    frag8 aF[4], bF[4];
#pragma unroll
    for (int mi = 0; mi < 4; ++mi) {
      const int row = wm * 64 + mi * 16 + laneN;
      aF[mi] = ld_frag(As + buf * 4096 + row * 32 +
                       ((quad ^ ((row >> 1) & 3)) * 8));
    }
#pragma unroll
    for (int ni = 0; ni < 4; ++ni) {
      const int row = wn * 64 + ni * 16 + laneN;
      bF[ni] = ld_frag(Bs + buf * 4096 + row * 32 +
                       ((quad ^ ((row >> 1) & 3)) * 8));
    }
#pragma unroll
    for (int mi = 0; mi < 4; ++mi)
#pragma unroll
      for (int ni = 0; ni < 4; ++ni)
        acc[mi][ni] = mfma_f16(aF[mi], bF[ni], acc[mi][ni]);
    RAW_BARRIER();
    buf = buf + 1 == 3 ? 0 : buf + 1;
  }

  // Epilogue. C/D: col = lane&15, row = quad*4 + reg.
#pragma unroll
  for (int mi = 0; mi < 4; ++mi)
#pragma unroll
    for (int ni = 0; ni < 4; ++ni) {
      const int colg = bn * 128 + wn * 64 + ni * 16 + laneN;
      const float bb = bias[colg];
      if (omode == 2) {
        // Vt [B,H,Hd,S]: r -> 4 consecutive s, same hd -> one b64 store
        const int rowg0 = bm * 128 + wm * 64 + mi * 16 + quad * 4;
        const int b = rowg0 >> 11, s0 = rowg0 & 2047;
        const int h = colg >> 6, hd = colg & 63;
        short pk[4];
#pragma unroll
        for (int r = 0; r < 4; ++r) pk[r] = f2h(acc[mi][ni][r] + bb);
        i32x2 w; __builtin_memcpy(&w, pk, 8);
        *(i32x2*)(Vt + (((size_t)(b * H_ + h)) * HD_ + hd) * S_ + s0) = w;
      } else {
#pragma unroll
        for (int r = 0; r < 4; ++r) {
          const int rowg = bm * 128 + wm * 64 + mi * 16 + quad * 4 + r;
          const int b = rowg >> 11, s = rowg & 2047;
          const int h = colg >> 6, hd = colg & 63;
          Out[(((size_t)(b * H_ + h)) * S_ + s) * HD_ + hd] =
              f2h((acc[mi][ni][r] + bb) * scale);
        }
      }
    }
}

// ---------------------------------------------------------------------------
// O projection: fp16 A x fp16 Wo -> fp32. Tile 128(M)x64(N), triple-buffered
// prefetch distance 2. A-GROUPED XCD DECODE: all 16 bn blocks sharing one
// A-tile (bm) on the same XCD (bm ≡ xcd mod 8); Wo (2 MB) fits per-XCD L2.
// ---------------------------------------------------------------------------
__global__ __launch_bounds__(256, 3)
void gemm_out(const short* __restrict__ Ap, const short* __restrict__ Wp,
              const float* __restrict__ bias, float* __restrict__ Out) {
  __shared__ short As[3 * 4096];   // 128x32
  __shared__ short Bs[3 * 2048];   // 64x32
  const int blk = blockIdx.x;
  const int xcd = blk & 7, i = blk >> 3;      // i in [0,64)
  const int bm = (i >> 4) * 8 + xcd;          // bm ≡ xcd (mod 8)
  const int bn = i & 15;

  const int t = threadIdx.x, wave = t >> 6, lane = t & 63;
  const int laneN = lane & 15, quad = lane >> 4;
  const int wm = wave & 1, wn = wave >> 1;

  f32x4 acc[4][2];
#pragma unroll
  for (int i2 = 0; i2 < 4; ++i2)
#pragma unroll
    for (int j = 0; j < 2; ++j)
#pragma unroll
      for (int r = 0; r < 4; ++r) acc[i2][j][r] = 0.f;

  auto stage = [&](int buf, int kk) {   // 3 asyncs/thread per call
#pragma unroll
    for (int j = 0; j < 2; ++j) {
      const int chunk = j * 256 + t;
      const int row = chunk >> 2;
      const int gg = (chunk & 3) ^ ((row >> 1) & 3);
      async_copy16(Ap + (size_t)(bm * 128 + row) * KDIM + kk + gg * 8,
                   As + buf * 4096 + chunk * 8);
    }
    {
      const int chunk = t;
      const int row = chunk >> 2;
      const int gg = (chunk & 3) ^ ((row >> 1) & 3);
      async_copy16(Wp + (size_t)(bn * 64 + row) * KDIM + kk + gg * 8,
                   Bs + buf * 2048 + chunk * 8);
    }
  };

  stage(0, 0);
  stage(1, 32);
  int buf = 0;
  for (int kk = 0; kk < KDIM; kk += 32) {
    if (kk + 64 < KDIM) {
      int nb = buf + 2; if (nb >= 3) nb -= 3;
      stage(nb, kk + 64);
      WAITCNT_VM(6);
    } else if (kk + 32 < KDIM) {
      WAITCNT_VM(3);
    } else {
      WAITCNT_VM(0);
    }
    RAW_BARRIER();

    frag8 aF[4], bF[2];
#pragma unroll
    for (int mi = 0; mi < 4; ++mi) {
      const int row = wm * 64 + mi * 16 + laneN;
      aF[mi] = ld_frag(As + buf * 4096 + row * 32 +
                       ((quad ^ ((row >> 1) & 3)) * 8));
    }
#pragma unroll
    for (int ni = 0; ni < 2; ++ni) {
      const int row = wn * 32 + ni * 16 + laneN;
      bF[ni] = ld_frag(Bs + buf * 2048 + row * 32 +
                       ((quad ^ ((row >> 1) & 3)) * 8));
    }
#pragma unroll
    for (int mi = 0; mi < 4; ++mi)
#pragma unroll
      for (int ni = 0; ni < 2; ++ni)
        acc[mi][ni] = mfma_f16(aF[mi], bF[ni], acc[mi][ni]);
    RAW_BARRIER();
    buf = buf + 1 == 3 ? 0 : buf + 1;
  }

#pragma unroll
  for (int mi = 0; mi < 4; ++mi)
#pragma unroll
    for (int ni = 0; ni < 2; ++ni) {
      const int colg = bn * 64 + wn * 32 + ni * 16 + laneN;
      const float bb = bias[colg];
#pragma unroll
      for (int r = 0; r < 4; ++r) {
        const int rowg = bm * 128 + wm * 64 + mi * 16 + quad * 4 + r;
        Out[(size_t)rowg * 1024 + colg] = acc[mi][ni][r] + bb;
      }
    }
}

// ---------------------------------------------------------------------------
// Flash attention, fp16, 512 threads = 8 waves x 16 q = 128 q/block
// (16 waves/CU — measured-best). XCD-aware grid (FETCH 69.7->12.3MB
// measured), __any rescale-skip, pk2h P-pack. Transposed scores
// mfma(A=K,B=Q) -> S^T; in-lane softmax + xor16/xor32; PV mfma(A=Vt,B=P)
// -> O^T. Double-buffered async staging. LDS 50KB -> 2 blocks/CU.
// ---------------------------------------------------------------------------
__global__ __launch_bounds__(512, 2)
void attn(const short* __restrict__ Qf, const short* __restrict__ Kf,
          const short* __restrict__ Vt_, short* __restrict__ Ow) {
  __shared__ short Ks[2 * 4096];
  __shared__ short Vts[2 * 4096];
  __shared__ short Ps[8][16 * 72];  // per-wave P strip [q][k], stride 72

  // XCD-locality: 512 blocks, 8 groups x 4 (h,b) pairs x 16 q-tiles
  const int blk = blockIdx.x;
  const int xcd = blk & 7, local = blk >> 3;
  const int pair = xcd * 4 + (local >> 4);
  const int h = pair & 15, b = pair >> 4, qt = local & 15;
  const size_t head = ((size_t)b * H_ + h) * (size_t)S_ * HD_;

  const int t = threadIdx.x;
  const int wave = t >> 6, lane = t & 63;
  const int laneN = lane & 15, quad = lane >> 4;

  // Q frags (B-operand); wave owns 16 q rows
  frag8 qf[2];
  {
    const size_t row = (size_t)qt * 128 + wave * 16 + laneN;
#pragma unroll
    for (int half = 0; half < 2; ++half)
      qf[half] = ld_frag(Qf + head + row * HD_ + half * 32 + quad * 8);
  }

  f32x4 o[4];          // O^T: row d = dt*16+quad*4+r, col q = laneN
  float m_r = -1e30f, l_r = 0.f;
#pragma unroll
  for (int i = 0; i < 4; ++i)
#pragma unroll
    for (int j = 0; j < 4; ++j) o[i][j] = 0.f;

  auto stage = [&](int buf, int kt) {   // 2 asyncs/thread
    const int chunk = t;                // 0..511
    const int row = chunk >> 3;         // 0..63
    const int g = (chunk & 7) ^ (row & 7);
    const int ldsoff = buf * 4096 + chunk * 8;
    async_copy16(Kf + head + (size_t)(kt * 64 + row) * HD_ + g * 8, Ks + ldsoff);
    async_copy16(Vt_ + head + (size_t)row * S_ + kt * 64 + g * 8, Vts + ldsoff);
  };

  stage(0, 0);
  int buf = 0;
  for (int kt = 0; kt < 32; ++kt, buf ^= 1) {
    if (kt + 1 < 32) {
      stage(buf ^ 1, kt + 1);
      WAITCNT_VM(2);
    } else {
      WAITCNT_VM(0);
    }
    RAW_BARRIER();

    // Vt frags (A-operand of PV): rows d = dt*16+laneN
    frag8 vf[4][2];
#pragma unroll
    for (int dt = 0; dt < 4; ++dt) {
      const int row = dt * 16 + laneN;
#pragma unroll
      for (int half = 0; half < 2; ++half)
        vf[dt][half] = ld_frag(Vts + buf * 4096 + row * 64 +
                               (((half * 4 + quad) ^ (row & 7)) * 8));
    }

    // S^T = K.Q^T: per lane 16 logits for q=laneN, k = nt*16+quad*4+r
    f32x4 s[4];
#pragma unroll
    for (int nt = 0; nt < 4; ++nt) {
      const int row = nt * 16 + laneN;
      const int o0 = buf * 4096 + row * 64 + ((quad ^ (row & 7)) * 8);
      const int o1 = buf * 4096 + row * 64 + (((quad + 4) ^ (row & 7)) * 8);
      frag8 k0 = ld_frag(Ks + o0), k1 = ld_frag(Ks + o1);
      f32x4 acc;
#pragma unroll
      for (int j = 0; j < 4; ++j) acc[j] = 0.f;
      acc = mfma_f16(k0, qf[0], acc);
      acc = mfma_f16(k1, qf[1], acc);
      s[nt] = acc;
    }

    // online softmax (exp2 domain): in-lane reduce 16 + xor16/xor32
    {
      float mx = -1e30f;
#pragma unroll
      for (int nt = 0; nt < 4; ++nt)
#pragma unroll
        for (int r = 0; r < 4; ++r) mx = fmaxf(mx, s[nt][r]);
      mx = fmaxf(mx, __shfl_xor(mx, 16));
      mx = fmaxf(mx, __shfl_xor(mx, 32));
      const float mold = m_r;
      const float mn = fmaxf(mold, mx);
      float rs = 0.f;
#pragma unroll
      for (int nt = 0; nt < 4; ++nt)
#pragma unroll
        for (int r = 0; r < 4; ++r) {
          const float p = fast_exp2(s[nt][r] - mn);
          s[nt][r] = p; rs += p;
        }
      rs += __shfl_xor(rs, 16);
      rs += __shfl_xor(rs, 32);
      if (__any(mn > mold)) {      // wave-uniform: rescale only if max grew
        const float al = fast_exp2(mold - mn);
        m_r = mn;
        l_r = l_r * al + rs;
#pragma unroll
        for (int dt = 0; dt < 4; ++dt)
#pragma unroll
          for (int r = 0; r < 4; ++r) o[dt][r] *= al;
      } else {
        l_r += rs;
      }
    }

    // P pack: 4 consecutive k per nt -> one b64 LDS write; strip [q][k]
#pragma unroll
    for (int nt = 0; nt < 4; ++nt) {
      i32x2 w;
      w[0] = pk2h(s[nt][0], s[nt][1]);
      w[1] = pk2h(s[nt][2], s[nt][3]);
      *(i32x2*)&Ps[wave][laneN * 72 + nt * 16 + quad * 4] = w;
    }
    // B-operand P frags (per-wave strip; in-order DS within a wave)
    const frag8 p0 = ld_frag(&Ps[wave][laneN * 72 + quad * 8]);
    const frag8 p1 = ld_frag(&Ps[wave][laneN * 72 + 32 + quad * 8]);
#pragma unroll
    for (int dt = 0; dt < 4; ++dt) {
      o[dt] = mfma_f16(vf[dt][0], p0, o[dt]);
      o[dt] = mfma_f16(vf[dt][1], p1, o[dt]);
    }
    RAW_BARRIER();
  }

  // epilogue: O^T -> Ow[B,S,D] fp16; lane owns q, 4 consecutive d per dt
  {
    const float inv = 1.0f / l_r;
    const int sg = qt * 128 + wave * 16 + laneN;
    short* dst = Ow + ((size_t)b * S_ + sg) * D_ + h * HD_;
#pragma unroll
    for (int dt = 0; dt < 4; ++dt) {
      short pk[4] = { f2h(o[dt][0] * inv), f2h(o[dt][1] * inv),
                      f2h(o[dt][2] * inv), f2h(o[dt][3] * inv) };
      i32x2 w; __builtin_memcpy(&w, pk, 8);
      *(i32x2*)(dst + dt * 16 + quad * 4) = w;
    }
  }
}

// ---------------------------------------------------------------------------
extern "C" void kernel_launch(void* const* d_in, const int* in_sizes, int n_in,
                              void* d_out, int out_size, void* d_ws, size_t ws_size,
                              hipStream_t stream) {
  const float* q  = (const float*)d_in[0];
  const float* k  = (const float*)d_in[1];
  const float* v  = (const float*)d_in[2];
  const float* Wq = (const float*)d_in[3];
  const float* bq = (const float*)d_in[4];
  const float* Wk = (const float*)d_in[5];
  const float* bk = (const float*)d_in[6];
  const float* Wv = (const float*)d_in[7];
  const float* bv = (const float*)d_in[8];
  const float* Wo = (const float*)d_in[9];
  const float* bo = (const float*)d_in[10];

  const size_t NTOK = (size_t)B_ * S_ * D_;   // 4,194,304
  const size_t NW   = (size_t)D_ * D_;        // 1,048,576
  short* p = (short*)d_ws;
  short* qh = p; p += NTOK;  short* kh = p; p += NTOK;  short* vh = p; p += NTOK;
  short* wq = p; p += NW;    short* wk = p; p += NW;
  short* wv = p; p += NW;    short* wo = p; p += NW;
  short* Qf = p; p += NTOK;  short* Kf = p; p += NTOK;
  short* Vt = p; p += NTOK;  short* Ow = p; p += NTOK;

  dim3 blk(256);

  conv_all<<<8192, blk, 0, stream>>>(q, k, v, Wq, Wk, Wv, Wo,
                                     qh, kh, vh, wq, wk, wv, wo);

  const float QS = 11.541560327111707f;  // 8 * log2(e): exp2-domain softmax
  gemm_qkv<<<768, blk, 0, stream>>>(qh, kh, vh, wq, wk, wv, bq, bk, bv,
                                    Qf, Kf, Vt, QS);

  attn<<<512, dim3(512), 0, stream>>>(Qf, Kf, Vt, Ow);

  gemm_out<<<512, blk, 0, stream>>>(Ow, wo, bo, (float*)d_out);
}